// Round 13
// baseline (322.231 us; speedup 1.0000x reference)
//
#include <hip/hip_runtime.h>

#define DIM 128
#define EPSF 1e-5f
#define BK_SHIFT 7            // 128 dst nodes per bucket -> 391 binB blocks (1.5 blocks/CU)
#define BK_NODES 128
#define GRP_SHIFT 13          // src octile: 8192-node window -> 2 MB L2 window (dense rows)
#define NGRP 8
#define BKS_CAP 768           // per (dst-bucket, src-octile): mean 256, +32 sigma
#define MAXNBS 3200           // 391*8 = 3128 sub-buckets

typedef __attribute__((ext_vector_type(8))) short short8;
typedef __attribute__((ext_vector_type(8))) unsigned short ushort8;
typedef __attribute__((ext_vector_type(4))) float float4v;

__device__ inline unsigned short f2bf(float x) {
    union { float f; unsigned u; } z; z.f = x;
    unsigned u = z.u;
    unsigned r = u + 0x7FFF + ((u >> 16) & 1);   // round-to-nearest-even
    return (unsigned short)(r >> 16);
}
__device__ inline float bf2f(unsigned short u) {
    union { unsigned u; float f; } z; z.u = ((unsigned)u) << 16;
    return z.f;
}

// ---------------------------------------------------------------- CSR build: 2-level counting sort
// 2048 edges/block (8/thread), 391 blocks: 2x binA parallelism vs 4096-edge tiles
// (R12 was 196 blocks = 0.77/CU, latency-bound on its two LDS passes).
__global__ void binA_kernel(const int* __restrict__ src, const int* __restrict__ dst,
                            unsigned* __restrict__ barr, int* __restrict__ bcnt,
                            int E, int NBS) {
    __shared__ int cnt[MAXNBS];
    __shared__ int gcur[MAXNBS];
    int tid = threadIdx.x;
    int tile0 = blockIdx.x * 2048;
    for (int j = tid; j < NBS; j += 256) cnt[j] = 0;
    __syncthreads();
    unsigned pk[8]; int bk[8];
#pragma unroll
    for (int i = 0; i < 8; ++i) {
        int e = tile0 + i * 256 + tid;
        if (e < E) {
            int d = dst[e];
            int s = src[e];
            bk[i] = ((d >> BK_SHIFT) << 3) | (s >> GRP_SHIFT);
            pk[i] = ((unsigned)(d & (BK_NODES - 1)) << 16) | (unsigned)s;
            atomicAdd(&cnt[bk[i]], 1);
        } else bk[i] = -1;
    }
    __syncthreads();
    for (int j = tid; j < NBS; j += 256) {
        int c = cnt[j];
        gcur[j] = (c > 0) ? atomicAdd(&bcnt[j], c) : 0;
    }
    __syncthreads();
#pragma unroll
    for (int i = 0; i < 8; ++i) {
        if (bk[i] >= 0) {
            int pos = atomicAdd(&gcur[bk[i]], 1);
            if (pos < BKS_CAP)
                barr[(size_t)bk[i] * BKS_CAP + pos] = pk[i];
        }
    }
}

// Pass B: one block per 128-node dst bucket (391 blocks); parallel prefix over bcnt,
// per-node hist (tid<128), 7-step scan, then 8 group-ordered scatter passes
// (keeps src-octile ordering inside each row). colidx as ushort (N < 65536).
__global__ void binB_kernel(const unsigned* __restrict__ barr, const int* __restrict__ bcnt,
                            int* __restrict__ rowptr, unsigned short* __restrict__ colidx,
                            int N, int E, int NBS) {
    __shared__ int hist[BK_NODES];
    __shared__ int sm[256];
    __shared__ int bc[NGRP];
    int b = blockIdx.x;
    int tid = threadIdx.x;
    int lim = b * NGRP;
    int part = 0;
    for (int i = tid; i < lim; i += 256) part += bcnt[i];
    sm[tid] = part;
    if (tid < NGRP) bc[tid] = bcnt[lim + tid];
    __syncthreads();
    for (int off = 128; off > 0; off >>= 1) {
        if (tid < off) sm[tid] += sm[tid + off];
        __syncthreads();
    }
    int gb = sm[0];
    if (b == 0 && tid == 0) rowptr[N] = E;
    __syncthreads();
    if (tid < BK_NODES) hist[tid] = 0;
    __syncthreads();
    for (int g = 0; g < NGRP; ++g) {
        int cg = bc[g]; if (cg > BKS_CAP) cg = BKS_CAP;
        const unsigned* arr = barr + (size_t)(b * NGRP + g) * BKS_CAP;
        for (int i = tid; i < cg; i += 256)
            atomicAdd(&hist[arr[i] >> 16], 1);
    }
    __syncthreads();
    int h = (tid < BK_NODES) ? hist[tid] : 0;
    sm[tid] = h;
    __syncthreads();
    for (int off = 1; off < BK_NODES; off <<= 1) {
        int x = (tid >= off && tid < BK_NODES) ? sm[tid - off] : 0;
        __syncthreads();
        if (tid < BK_NODES) sm[tid] += x;
        __syncthreads();
    }
    if (tid < BK_NODES) {
        int base = sm[tid] - h;                 // exclusive scan
        hist[tid] = base;
        int node = (b << BK_SHIFT) + tid;
        if (node < N) rowptr[node] = gb + base;
    }
    __syncthreads();
    for (int g = 0; g < NGRP; ++g) {
        int cg = bc[g]; if (cg > BKS_CAP) cg = BKS_CAP;
        const unsigned* arr = barr + (size_t)(b * NGRP + g) * BKS_CAP;
        for (int i = tid; i < cg; i += 256) {
            unsigned u = arr[i];
            int pos = atomicAdd(&hist[u >> 16], 1);
            colidx[gb + pos] = (unsigned short)(u & 0xFFFFu);
        }
        __syncthreads();
    }
}

// ---------------------------------------------------------------- prep: weight pack (blocks 0..23)
// + zero bcnt/stats (block 24) + feat fp32 -> bf16 dense Hb (blocks 25..)
__global__ void prep_kernel(const float* __restrict__ Ws, const float* __restrict__ Wn,
                            unsigned short* __restrict__ wpack,
                            const float* __restrict__ feat, unsigned short* __restrict__ Hb,
                            int* __restrict__ zbase, int N) {
    int b = blockIdx.x;
    int tid = threadIdx.x;
    if (b < 24) {
        int l = b >> 3;
        int s = b & 7;
#pragma unroll
        for (int pi = 0; pi < 2; ++pi) {
            int p = tid * 2 + pi;
            int nt = p >> 6;
            int lane = p & 63;
            int kb = s * 32 + (lane >> 4) * 8;
            int col = nt * 16 + (lane & 15);
            unsigned short* dstp = wpack + (size_t)l * 32768 + ((size_t)(s * 8 + nt) * 64 + lane) * 8;
#pragma unroll
            for (int j = 0; j < 8; ++j) {
                int k = kb + j;
                float v = (k < 128) ? Ws[(size_t)l * 16384 + k * 128 + col]
                                    : Wn[(size_t)l * 16384 + (k - 128) * 128 + col];
                dstp[j] = f2bf(v);
            }
        }
        return;
    }
    if (b == 24) {
        for (int j = tid; j < MAXNBS + 512; j += 256) zbase[j] = 0;   // bcnt + 2 stats slots
        return;
    }
    int idx = (b - 25) * 256 + tid;    // float4 units
    if (idx >= N * 32) return;
    float4 v = ((const float4*)feat)[idx];
    ushort4 o;
    o.x = f2bf(v.x); o.y = f2bf(v.y); o.z = f2bf(v.z); o.w = f2bf(v.w);
    ((ushort4*)Hb)[idx] = o;
}

// ---------------------------------------------------------------- mean aggregation (quarter-wave rows)
// ONE WAVE per node; quarter-wave (16 lanes x ushort8 = full 256 B row) per neighbor,
// unroll-4 per quarter -> 16 rows in flight per wave. Register accumulation only
// (R10: LDS-atomic accumulation is ~50x slower). Reduce across quarters via shfl_xor.
__global__ void aggregate_kernel(const unsigned short* __restrict__ Hb,
                                 unsigned short* __restrict__ Agg,
                                 const int* __restrict__ rowptr,
                                 const unsigned short* __restrict__ colidx, int N) {
    int wid = (blockIdx.x * blockDim.x + threadIdx.x) >> 6;
    if (wid >= N) return;
    int lane = threadIdx.x & 63;
    int q = lane >> 4, ql = lane & 15;
    int beg = rowptr[wid], end = rowptr[wid + 1];
    float a[8];
#pragma unroll
    for (int j = 0; j < 8; ++j) a[j] = 0.f;
    int e = beg + q;
    for (; e + 12 < end; e += 16) {
        int s0 = colidx[e];
        int s1 = colidx[e + 4];
        int s2 = colidx[e + 8];
        int s3 = colidx[e + 12];
        ushort8 u0 = *(const ushort8*)(Hb + (size_t)s0 * 128 + ql * 8);
        ushort8 u1 = *(const ushort8*)(Hb + (size_t)s1 * 128 + ql * 8);
        ushort8 u2 = *(const ushort8*)(Hb + (size_t)s2 * 128 + ql * 8);
        ushort8 u3 = *(const ushort8*)(Hb + (size_t)s3 * 128 + ql * 8);
#pragma unroll
        for (int j = 0; j < 8; ++j)
            a[j] += (bf2f((unsigned short)u0[j]) + bf2f((unsigned short)u1[j]))
                  + (bf2f((unsigned short)u2[j]) + bf2f((unsigned short)u3[j]));
    }
    for (; e < end; e += 4) {
        int s0 = colidx[e];
        ushort8 u0 = *(const ushort8*)(Hb + (size_t)s0 * 128 + ql * 8);
#pragma unroll
        for (int j = 0; j < 8; ++j) a[j] += bf2f((unsigned short)u0[j]);
    }
#pragma unroll
    for (int j = 0; j < 8; ++j) {
        a[j] += __shfl_xor(a[j], 16);
        a[j] += __shfl_xor(a[j], 32);
    }
    if (q == 0) {
        int deg = end - beg;
        float inv = 1.0f / (float)(deg > 0 ? deg : 1);
        ushort8 o;
#pragma unroll
        for (int j = 0; j < 8; ++j) o[j] = f2bf(a[j] * inv);
        *(ushort8*)(Agg + (size_t)wid * 128 + ql * 8) = o;
    }
}

// ---------------------------------------------------------------- MFMA GEMM: [Hb | Agg] (Nx256) @ Wcat(256x128)
// + bias + bf16 residual (Hb). 256-row tile, 512 threads (R11-verified).
__launch_bounds__(512)
__global__ void gemm_kernel(const unsigned short* __restrict__ Hb,
                            const unsigned short* __restrict__ Agg,
                            const unsigned short* __restrict__ wpack,
                            const float* __restrict__ bias,
                            unsigned short* __restrict__ outb, float* __restrict__ outf,
                            float* __restrict__ stats, int withStats, int N) {
    __shared__ unsigned short Bs[32768];   // 64 KB, fragment-major
    int tid = threadIdx.x;
    {
        const float4* wsrc = (const float4*)wpack;
        float4* bdst = (float4*)Bs;
#pragma unroll
        for (int i = 0; i < 8; ++i) bdst[i * 512 + tid] = wsrc[i * 512 + tid];
    }
    __syncthreads();

    int wave = tid >> 6, lane = tid & 63;
    int row0 = blockIdx.x * 256 + wave * 32;
    int mrow = lane & 15, kq = lane >> 4;
    const unsigned short* Sbase = Hb + (size_t)(row0 + mrow) * 128 + kq * 8;
    const unsigned short* Gbase = Agg + (size_t)(row0 + mrow) * 128 + kq * 8;

    float4v acc[2][8];
#pragma unroll
    for (int i = 0; i < 2; ++i)
#pragma unroll
        for (int j = 0; j < 8; ++j) acc[i][j] = (float4v){0.f, 0.f, 0.f, 0.f};

#pragma unroll
    for (int s = 0; s < 8; ++s) {
        const unsigned short* ab = (s < 4) ? (Sbase + s * 32) : (Gbase + (s - 4) * 32);
        short8 a0 = *(const short8*)ab;
        short8 a1 = *(const short8*)(ab + 16 * 128);
#pragma unroll
        for (int nt = 0; nt < 8; ++nt) {
            short8 b = *(const short8*)(Bs + ((size_t)(s * 8 + nt) * 64 + lane) * 8);
            acc[0][nt] = __builtin_amdgcn_mfma_f32_16x16x32_bf16(a0, b, acc[0][nt], 0, 0, 0);
            acc[1][nt] = __builtin_amdgcn_mfma_f32_16x16x32_bf16(a1, b, acc[1][nt], 0, 0, 0);
        }
    }

    float* sm = (float*)Bs;
    if (withStats) {
        __syncthreads();
        if (tid < 256) sm[tid] = 0.f;
        __syncthreads();
    }

    int colb = lane & 15;
    int rq = (lane >> 4) * 4;              // C layout: col = lane&15, row = (lane>>4)*4 + reg
#pragma unroll
    for (int mt = 0; mt < 2; ++mt) {
        int rowt = row0 + mt * 16 + rq;
#pragma unroll
        for (int nt = 0; nt < 8; ++nt) {
            int col = nt * 16 + colb;
            float bv = bias[col];
            float slo = 0.f, qlo = 0.f;
#pragma unroll
            for (int r = 0; r < 4; ++r) {
                int row = rowt + r;
                if (row < N) {
                    float res = bf2f(Hb[(size_t)row * 128 + col]);
                    float v = acc[mt][nt][r] + bv + res;
                    if (withStats) {
                        outb[(size_t)row * 128 + col] = f2bf(v);
                        slo += v; qlo += v * v;
                    } else {
                        outf[(size_t)row * 128 + col] = v;
                    }
                }
            }
            if (withStats) {
                atomicAdd(&sm[col], slo);
                atomicAdd(&sm[128 + col], qlo);
            }
        }
    }
    if (withStats) {
        __syncthreads();
        if (tid < 128) {
            atomicAdd(&stats[tid], sm[tid]);
            atomicAdd(&stats[128 + tid], sm[128 + tid]);
        }
    }
}

// ---------------------------------------------------------------- BN apply + ReLU, once per node
// dense: Hd (raw hn bf16) -> Hb (BN'd h bf16)
__global__ void bn_kernel(const unsigned short* __restrict__ hn,
                          unsigned short* __restrict__ Hb,
                          const float* __restrict__ stats, const float* __restrict__ gamma,
                          const float* __restrict__ beta, float invN, int N) {
    __shared__ float sc_s[128], sh_s[128];
    int tid = threadIdx.x;
    if (tid < 128) {
        float mean = stats[tid] * invN;
        float var = stats[128 + tid] * invN - mean * mean;
        float sc = gamma[tid] * rsqrtf(var + EPSF);
        sc_s[tid] = sc;
        sh_s[tid] = beta[tid] - mean * sc;
    }
    __syncthreads();
    int idx = blockIdx.x * 256 + tid;      // ushort4 units
    if (idx >= N * 32) return;
    int c4 = idx & 31;
    ushort4 u = *(const ushort4*)(hn + (size_t)idx * 4);
    ushort4 o;
    {
        int col = c4 * 4;
        float v0 = fmaf(bf2f(u.x), sc_s[col], sh_s[col]);
        float v1 = fmaf(bf2f(u.y), sc_s[col + 1], sh_s[col + 1]);
        float v2 = fmaf(bf2f(u.z), sc_s[col + 2], sh_s[col + 2]);
        float v3 = fmaf(bf2f(u.w), sc_s[col + 3], sh_s[col + 3]);
        o.x = f2bf(fmaxf(v0, 0.f));
        o.y = f2bf(fmaxf(v1, 0.f));
        o.z = f2bf(fmaxf(v2, 0.f));
        o.w = f2bf(fmaxf(v3, 0.f));
    }
    *(ushort4*)(Hb + (size_t)idx * 4) = o;
}

// ---------------------------------------------------------------- launch
extern "C" void kernel_launch(void* const* d_in, const int* in_sizes, int n_in,
                              void* d_out, int out_size, void* d_ws, size_t ws_size,
                              hipStream_t stream) {
    const float* feat  = (const float*)d_in[0];
    const int*   src   = (const int*)d_in[1];
    const int*   dst   = (const int*)d_in[2];
    const float* Wself = (const float*)d_in[3];
    const float* Wneig = (const float*)d_in[4];
    const float* bias  = (const float*)d_in[5];
    const float* gamma = (const float*)d_in[6];
    const float* beta  = (const float*)d_in[7];

    int N = in_sizes[0] / DIM;
    int E = in_sizes[1];
    int Npad = (N + 255) & ~255;               // 256-row gemm tiles
    int NB = (N + BK_NODES - 1) >> BK_SHIFT;   // 391 for N=50000
    int NBS = NB * NGRP;                       // 3128 sub-buckets (<=3200)

    char* ws = (char*)d_ws;
    size_t off = 0;
    auto alloc = [&](size_t bytes) -> void* {
        void* p = ws + off;
        off = (off + bytes + 255) & ~(size_t)255;
        return p;
    };
    unsigned short* Hb    = (unsigned short*)alloc((size_t)Npad * 128 * 2);  // BN'd h / input
    unsigned short* Agg   = (unsigned short*)alloc((size_t)Npad * 128 * 2);  // mean agg
    unsigned short* Hd    = (unsigned short*)alloc((size_t)Npad * 128 * 2);  // raw hn
    unsigned short* wpack = (unsigned short*)alloc((size_t)3 * 32768 * 2);
    unsigned short* colidx = (unsigned short*)alloc((size_t)E * 2);
    int*   rowptr = (int*)alloc((size_t)(N + 1) * 4);
    int*   bcnt   = (int*)alloc(MAXNBS * 4);   // 12800 B (256-mult) -> stats contiguous
    float* stats  = (float*)alloc(512 * 4);    // 2 layer slots of [sum|sumsq]x128

    // bucket array aliases Agg (dead until the first aggregate phase writes it)
    unsigned* barr = (unsigned*)Agg;   // 3128 * 768 * 4 = 9.61 MB <= 12.85 MB

    float invN = 1.0f / (float)N;
    int nagg = (N + 3) / 4;
    int nbn  = (N * 32 + 255) / 256;

    // prep zeroes bcnt+stats (block 24) before binA runs (stream-serial)
    prep_kernel<<<25 + nbn, 256, 0, stream>>>(Wself, Wneig, wpack, feat, Hb, bcnt, N);
    binA_kernel<<<(E + 2047) / 2048, 256, 0, stream>>>(src, dst, barr, bcnt, E, NBS);
    binB_kernel<<<NB, 256, 0, stream>>>(barr, bcnt, rowptr, colidx, N, E, NBS);

    // layer 0
    aggregate_kernel<<<nagg, 256, 0, stream>>>(Hb, Agg, rowptr, colidx, N);
    gemm_kernel<<<Npad / 256, 512, 0, stream>>>(Hb, Agg, wpack, bias,
                                                Hd, (float*)d_out, stats, 1, N);
    bn_kernel<<<nbn, 256, 0, stream>>>(Hd, Hb, stats, gamma, beta, invN, N);
    // layer 1
    aggregate_kernel<<<nagg, 256, 0, stream>>>(Hb, Agg, rowptr, colidx, N);
    gemm_kernel<<<Npad / 256, 512, 0, stream>>>(Hb, Agg, wpack + 32768, bias + DIM,
                                                Hd, (float*)d_out, stats + 256, 1, N);
    bn_kernel<<<nbn, 256, 0, stream>>>(Hd, Hb, stats + 256, gamma + DIM, beta + DIM, invN, N);
    // layer 2 (final: fp32 out, no stats)
    aggregate_kernel<<<nagg, 256, 0, stream>>>(Hb, Agg, rowptr, colidx, N);
    gemm_kernel<<<Npad / 256, 512, 0, stream>>>(Hb, Agg, wpack + 2 * 32768, bias + 2 * DIM,
                                                Hd, (float*)d_out, stats, 0, N);
}

// Round 14
// 316.900 us; speedup vs baseline: 1.0168x; 1.0168x over previous
//
#include <hip/hip_runtime.h>

#define DIM 128
#define EPSF 1e-5f
#define BK_SHIFT 8            // 256 dst nodes per bucket -> 196 binB blocks
#define BK_NODES 256
#define GRP_SHIFT 13          // src octile: 8192-node window -> 2 MB L2 window (dense rows)
#define NGRP 8
#define BKS_CAP 1536          // per (dst-bucket, src-octile): mean 671, +32 sigma
#define MAXNBS 1600

typedef __attribute__((ext_vector_type(8))) short short8;
typedef __attribute__((ext_vector_type(8))) unsigned short ushort8;
typedef __attribute__((ext_vector_type(4))) float float4v;

__device__ inline unsigned short f2bf(float x) {
    union { float f; unsigned u; } z; z.f = x;
    unsigned u = z.u;
    unsigned r = u + 0x7FFF + ((u >> 16) & 1);   // round-to-nearest-even
    return (unsigned short)(r >> 16);
}
__device__ inline float bf2f(unsigned short u) {
    union { unsigned u; float f; } z; z.u = ((unsigned)u) << 16;
    return z.f;
}

// ---------------------------------------------------------------- CSR build: 2-level counting sort
// 4096 edges/block: binA per-block FIXED cost is LDS-init+prefix over 1568 sub-buckets,
// so fewer, fatter blocks win (R13 proved 2048-edge tiles regress ~4 us).
__global__ void binA_kernel(const int* __restrict__ src, const int* __restrict__ dst,
                            unsigned* __restrict__ barr, int* __restrict__ bcnt,
                            int E, int NBS) {
    __shared__ int cnt[MAXNBS];
    __shared__ int gcur[MAXNBS];
    int tid = threadIdx.x;
    int tile0 = blockIdx.x * 4096;
    for (int j = tid; j < NBS; j += 256) cnt[j] = 0;
    __syncthreads();
    unsigned pk[16]; int bk[16];
#pragma unroll
    for (int i = 0; i < 16; ++i) {
        int e = tile0 + i * 256 + tid;
        if (e < E) {
            int d = dst[e];
            int s = src[e];
            bk[i] = ((d >> BK_SHIFT) << 3) | (s >> GRP_SHIFT);
            pk[i] = ((unsigned)(d & (BK_NODES - 1)) << 16) | (unsigned)s;
            atomicAdd(&cnt[bk[i]], 1);
        } else bk[i] = -1;
    }
    __syncthreads();
    for (int j = tid; j < NBS; j += 256) {
        int c = cnt[j];
        gcur[j] = (c > 0) ? atomicAdd(&bcnt[j], c) : 0;
    }
    __syncthreads();
#pragma unroll
    for (int i = 0; i < 16; ++i) {
        if (bk[i] >= 0) {
            int pos = atomicAdd(&gcur[bk[i]], 1);
            if (pos < BKS_CAP)
                barr[(size_t)bk[i] * BKS_CAP + pos] = pk[i];
        }
    }
}

// Pass B: one block per 256-node dst bucket; parallel prefix, per-node hist (1 node/thread),
// scan, then 8 group-ordered scatter passes (keeps src-octile ordering inside each row).
// colidx written as ushort (N < 65536): halves index traffic for the 3 gathers.
__global__ void binB_kernel(const unsigned* __restrict__ barr, const int* __restrict__ bcnt,
                            int* __restrict__ rowptr, unsigned short* __restrict__ colidx,
                            int N, int E, int NBS) {
    __shared__ int hist[256];
    __shared__ int sm[256];
    __shared__ int bc[NGRP];
    int b = blockIdx.x;
    int tid = threadIdx.x;
    int lim = b * NGRP;
    int part = 0;
    for (int i = tid; i < lim; i += 256) part += bcnt[i];
    sm[tid] = part;
    if (tid < NGRP) bc[tid] = bcnt[lim + tid];
    __syncthreads();
    for (int off = 128; off > 0; off >>= 1) {
        if (tid < off) sm[tid] += sm[tid + off];
        __syncthreads();
    }
    int gb = sm[0];
    if (b == 0 && tid == 0) rowptr[N] = E;
    __syncthreads();
    hist[tid] = 0;
    __syncthreads();
    for (int g = 0; g < NGRP; ++g) {
        int cg = bc[g]; if (cg > BKS_CAP) cg = BKS_CAP;
        const unsigned* arr = barr + (size_t)(b * NGRP + g) * BKS_CAP;
        for (int i = tid; i < cg; i += 256)
            atomicAdd(&hist[arr[i] >> 16], 1);
    }
    __syncthreads();
    int h = hist[tid];
    sm[tid] = h;
    __syncthreads();
    for (int off = 1; off < 256; off <<= 1) {
        int x = (tid >= off) ? sm[tid - off] : 0;
        __syncthreads();
        sm[tid] += x;
        __syncthreads();
    }
    int base = sm[tid] - h;
    hist[tid] = base;
    int node = (b << BK_SHIFT) + tid;
    if (node < N) rowptr[node] = gb + base;
    __syncthreads();
    for (int g = 0; g < NGRP; ++g) {
        int cg = bc[g]; if (cg > BKS_CAP) cg = BKS_CAP;
        const unsigned* arr = barr + (size_t)(b * NGRP + g) * BKS_CAP;
        for (int i = tid; i < cg; i += 256) {
            unsigned u = arr[i];
            int pos = atomicAdd(&hist[u >> 16], 1);
            colidx[gb + pos] = (unsigned short)(u & 0xFFFFu);
        }
        __syncthreads();
    }
}

// ---------------------------------------------------------------- prep: weight pack (blocks 0..23)
// + zero bcnt/stats (block 24) + feat fp32 -> bf16 dense Hb (blocks 25..)
__global__ void prep_kernel(const float* __restrict__ Ws, const float* __restrict__ Wn,
                            unsigned short* __restrict__ wpack,
                            const float* __restrict__ feat, unsigned short* __restrict__ Hb,
                            int* __restrict__ zbase, int N) {
    int b = blockIdx.x;
    int tid = threadIdx.x;
    if (b < 24) {
        int l = b >> 3;
        int s = b & 7;
#pragma unroll
        for (int pi = 0; pi < 2; ++pi) {
            int p = tid * 2 + pi;
            int nt = p >> 6;
            int lane = p & 63;
            int kb = s * 32 + (lane >> 4) * 8;
            int col = nt * 16 + (lane & 15);
            unsigned short* dstp = wpack + (size_t)l * 32768 + ((size_t)(s * 8 + nt) * 64 + lane) * 8;
#pragma unroll
            for (int j = 0; j < 8; ++j) {
                int k = kb + j;
                float v = (k < 128) ? Ws[(size_t)l * 16384 + k * 128 + col]
                                    : Wn[(size_t)l * 16384 + (k - 128) * 128 + col];
                dstp[j] = f2bf(v);
            }
        }
        return;
    }
    if (b == 24) {
        for (int j = tid; j < MAXNBS + 512; j += 256) zbase[j] = 0;   // bcnt + 2 stats slots
        return;
    }
    int idx = (b - 25) * 256 + tid;    // float4 units
    if (idx >= N * 32) return;
    float4 v = ((const float4*)feat)[idx];
    ushort4 o;
    o.x = f2bf(v.x); o.y = f2bf(v.y); o.z = f2bf(v.z); o.w = f2bf(v.w);
    ((ushort4*)Hb)[idx] = o;
}

// ---------------------------------------------------------------- mean aggregation (quarter-wave rows)
// ONE WAVE per node; quarter-wave (16 lanes x ushort8 = full 256 B row) per neighbor,
// unroll-4 per quarter -> 16 rows in flight per wave. Register accumulation only
// (R10: LDS-atomic accumulation is ~50x slower). Reduce across quarters via shfl_xor.
__global__ void aggregate_kernel(const unsigned short* __restrict__ Hb,
                                 unsigned short* __restrict__ Agg,
                                 const int* __restrict__ rowptr,
                                 const unsigned short* __restrict__ colidx, int N) {
    int wid = (blockIdx.x * blockDim.x + threadIdx.x) >> 6;
    if (wid >= N) return;
    int lane = threadIdx.x & 63;
    int q = lane >> 4, ql = lane & 15;
    int beg = rowptr[wid], end = rowptr[wid + 1];
    float a[8];
#pragma unroll
    for (int j = 0; j < 8; ++j) a[j] = 0.f;
    int e = beg + q;
    for (; e + 12 < end; e += 16) {
        int s0 = colidx[e];
        int s1 = colidx[e + 4];
        int s2 = colidx[e + 8];
        int s3 = colidx[e + 12];
        ushort8 u0 = *(const ushort8*)(Hb + (size_t)s0 * 128 + ql * 8);
        ushort8 u1 = *(const ushort8*)(Hb + (size_t)s1 * 128 + ql * 8);
        ushort8 u2 = *(const ushort8*)(Hb + (size_t)s2 * 128 + ql * 8);
        ushort8 u3 = *(const ushort8*)(Hb + (size_t)s3 * 128 + ql * 8);
#pragma unroll
        for (int j = 0; j < 8; ++j)
            a[j] += (bf2f((unsigned short)u0[j]) + bf2f((unsigned short)u1[j]))
                  + (bf2f((unsigned short)u2[j]) + bf2f((unsigned short)u3[j]));
    }
    for (; e < end; e += 4) {
        int s0 = colidx[e];
        ushort8 u0 = *(const ushort8*)(Hb + (size_t)s0 * 128 + ql * 8);
#pragma unroll
        for (int j = 0; j < 8; ++j) a[j] += bf2f((unsigned short)u0[j]);
    }
#pragma unroll
    for (int j = 0; j < 8; ++j) {
        a[j] += __shfl_xor(a[j], 16);
        a[j] += __shfl_xor(a[j], 32);
    }
    if (q == 0) {
        int deg = end - beg;
        float inv = 1.0f / (float)(deg > 0 ? deg : 1);
        ushort8 o;
#pragma unroll
        for (int j = 0; j < 8; ++j) o[j] = f2bf(a[j] * inv);
        *(ushort8*)(Agg + (size_t)wid * 128 + ql * 8) = o;
    }
}

// ---------------------------------------------------------------- MFMA GEMM: [Hb | Agg] (Nx256) @ Wcat(256x128)
// + bias + bf16 residual (Hb). 256-row tile, 512 threads, 64 KB LDS B-stage (R11-verified).
__launch_bounds__(512)
__global__ void gemm_kernel(const unsigned short* __restrict__ Hb,
                            const unsigned short* __restrict__ Agg,
                            const unsigned short* __restrict__ wpack,
                            const float* __restrict__ bias,
                            unsigned short* __restrict__ outb, float* __restrict__ outf,
                            float* __restrict__ stats, int withStats, int N) {
    __shared__ unsigned short Bs[32768];   // 64 KB, fragment-major
    int tid = threadIdx.x;
    {
        const float4* wsrc = (const float4*)wpack;
        float4* bdst = (float4*)Bs;
#pragma unroll
        for (int i = 0; i < 8; ++i) bdst[i * 512 + tid] = wsrc[i * 512 + tid];
    }
    __syncthreads();

    int wave = tid >> 6, lane = tid & 63;
    int row0 = blockIdx.x * 256 + wave * 32;
    int mrow = lane & 15, kq = lane >> 4;
    const unsigned short* Sbase = Hb + (size_t)(row0 + mrow) * 128 + kq * 8;
    const unsigned short* Gbase = Agg + (size_t)(row0 + mrow) * 128 + kq * 8;

    float4v acc[2][8];
#pragma unroll
    for (int i = 0; i < 2; ++i)
#pragma unroll
        for (int j = 0; j < 8; ++j) acc[i][j] = (float4v){0.f, 0.f, 0.f, 0.f};

#pragma unroll
    for (int s = 0; s < 8; ++s) {
        const unsigned short* ab = (s < 4) ? (Sbase + s * 32) : (Gbase + (s - 4) * 32);
        short8 a0 = *(const short8*)ab;
        short8 a1 = *(const short8*)(ab + 16 * 128);
#pragma unroll
        for (int nt = 0; nt < 8; ++nt) {
            short8 b = *(const short8*)(Bs + ((size_t)(s * 8 + nt) * 64 + lane) * 8);
            acc[0][nt] = __builtin_amdgcn_mfma_f32_16x16x32_bf16(a0, b, acc[0][nt], 0, 0, 0);
            acc[1][nt] = __builtin_amdgcn_mfma_f32_16x16x32_bf16(a1, b, acc[1][nt], 0, 0, 0);
        }
    }

    float* sm = (float*)Bs;
    if (withStats) {
        __syncthreads();
        if (tid < 256) sm[tid] = 0.f;
        __syncthreads();
    }

    int colb = lane & 15;
    int rq = (lane >> 4) * 4;              // C layout: col = lane&15, row = (lane>>4)*4 + reg
#pragma unroll
    for (int mt = 0; mt < 2; ++mt) {
        int rowt = row0 + mt * 16 + rq;
#pragma unroll
        for (int nt = 0; nt < 8; ++nt) {
            int col = nt * 16 + colb;
            float bv = bias[col];
            float slo = 0.f, qlo = 0.f;
#pragma unroll
            for (int r = 0; r < 4; ++r) {
                int row = rowt + r;
                if (row < N) {
                    float res = bf2f(Hb[(size_t)row * 128 + col]);
                    float v = acc[mt][nt][r] + bv + res;
                    if (withStats) {
                        outb[(size_t)row * 128 + col] = f2bf(v);
                        slo += v; qlo += v * v;
                    } else {
                        outf[(size_t)row * 128 + col] = v;
                    }
                }
            }
            if (withStats) {
                atomicAdd(&sm[col], slo);
                atomicAdd(&sm[128 + col], qlo);
            }
        }
    }
    if (withStats) {
        __syncthreads();
        if (tid < 128) {
            atomicAdd(&stats[tid], sm[tid]);
            atomicAdd(&stats[128 + tid], sm[128 + tid]);
        }
    }
}

// ---------------------------------------------------------------- BN apply + ReLU, once per node
// dense: Hd (raw hn bf16) -> Hb (BN'd h bf16)
__global__ void bn_kernel(const unsigned short* __restrict__ hn,
                          unsigned short* __restrict__ Hb,
                          const float* __restrict__ stats, const float* __restrict__ gamma,
                          const float* __restrict__ beta, float invN, int N) {
    __shared__ float sc_s[128], sh_s[128];
    int tid = threadIdx.x;
    if (tid < 128) {
        float mean = stats[tid] * invN;
        float var = stats[128 + tid] * invN - mean * mean;
        float sc = gamma[tid] * rsqrtf(var + EPSF);
        sc_s[tid] = sc;
        sh_s[tid] = beta[tid] - mean * sc;
    }
    __syncthreads();
    int idx = blockIdx.x * 256 + tid;      // ushort4 units
    if (idx >= N * 32) return;
    int c4 = idx & 31;
    ushort4 u = *(const ushort4*)(hn + (size_t)idx * 4);
    ushort4 o;
    {
        int col = c4 * 4;
        float v0 = fmaf(bf2f(u.x), sc_s[col], sh_s[col]);
        float v1 = fmaf(bf2f(u.y), sc_s[col + 1], sh_s[col + 1]);
        float v2 = fmaf(bf2f(u.z), sc_s[col + 2], sh_s[col + 2]);
        float v3 = fmaf(bf2f(u.w), sc_s[col + 3], sh_s[col + 3]);
        o.x = f2bf(fmaxf(v0, 0.f));
        o.y = f2bf(fmaxf(v1, 0.f));
        o.z = f2bf(fmaxf(v2, 0.f));
        o.w = f2bf(fmaxf(v3, 0.f));
    }
    *(ushort4*)(Hb + (size_t)idx * 4) = o;
}

// ---------------------------------------------------------------- launch
extern "C" void kernel_launch(void* const* d_in, const int* in_sizes, int n_in,
                              void* d_out, int out_size, void* d_ws, size_t ws_size,
                              hipStream_t stream) {
    const float* feat  = (const float*)d_in[0];
    const int*   src   = (const int*)d_in[1];
    const int*   dst   = (const int*)d_in[2];
    const float* Wself = (const float*)d_in[3];
    const float* Wneig = (const float*)d_in[4];
    const float* bias  = (const float*)d_in[5];
    const float* gamma = (const float*)d_in[6];
    const float* beta  = (const float*)d_in[7];

    int N = in_sizes[0] / DIM;
    int E = in_sizes[1];
    int Npad = (N + 255) & ~255;               // 256-row gemm tiles
    int NB = (N + BK_NODES - 1) >> BK_SHIFT;   // 196 for N=50000
    int NBS = NB * NGRP;                       // 1568 sub-buckets (<=1600)

    char* ws = (char*)d_ws;
    size_t off = 0;
    auto alloc = [&](size_t bytes) -> void* {
        void* p = ws + off;
        off = (off + bytes + 255) & ~(size_t)255;
        return p;
    };
    unsigned short* Hb    = (unsigned short*)alloc((size_t)Npad * 128 * 2);  // BN'd h / input
    unsigned short* Agg   = (unsigned short*)alloc((size_t)Npad * 128 * 2);  // mean agg
    unsigned short* Hd    = (unsigned short*)alloc((size_t)Npad * 128 * 2);  // raw hn
    unsigned short* wpack = (unsigned short*)alloc((size_t)3 * 32768 * 2);
    unsigned short* colidx = (unsigned short*)alloc((size_t)E * 2);
    int*   rowptr = (int*)alloc((size_t)(N + 1) * 4);
    int*   bcnt   = (int*)alloc(MAXNBS * 4);   // 6400 B (256-mult) -> stats contiguous
    float* stats  = (float*)alloc(512 * 4);    // 2 layer slots of [sum|sumsq]x128

    // bucket array aliases Agg (dead until the first aggregate phase writes it)
    unsigned* barr = (unsigned*)Agg;   // 1568 * 1536 * 4 = 9.63 MB <= 12.85 MB

    float invN = 1.0f / (float)N;
    int nagg = (N + 3) / 4;
    int nbn  = (N * 32 + 255) / 256;

    // prep zeroes bcnt+stats (block 24) before binA runs (stream-serial)
    prep_kernel<<<25 + nbn, 256, 0, stream>>>(Wself, Wneig, wpack, feat, Hb, bcnt, N);
    binA_kernel<<<(E + 4095) / 4096, 256, 0, stream>>>(src, dst, barr, bcnt, E, NBS);
    binB_kernel<<<NB, 256, 0, stream>>>(barr, bcnt, rowptr, colidx, N, E, NBS);

    // layer 0
    aggregate_kernel<<<nagg, 256, 0, stream>>>(Hb, Agg, rowptr, colidx, N);
    gemm_kernel<<<Npad / 256, 512, 0, stream>>>(Hb, Agg, wpack, bias,
                                                Hd, (float*)d_out, stats, 1, N);
    bn_kernel<<<nbn, 256, 0, stream>>>(Hd, Hb, stats, gamma, beta, invN, N);
    // layer 1
    aggregate_kernel<<<nagg, 256, 0, stream>>>(Hb, Agg, rowptr, colidx, N);
    gemm_kernel<<<Npad / 256, 512, 0, stream>>>(Hb, Agg, wpack + 32768, bias + DIM,
                                                Hd, (float*)d_out, stats + 256, 1, N);
    bn_kernel<<<nbn, 256, 0, stream>>>(Hd, Hb, stats + 256, gamma + DIM, beta + DIM, invN, N);
    // layer 2 (final: fp32 out, no stats)
    aggregate_kernel<<<nagg, 256, 0, stream>>>(Hb, Agg, rowptr, colidx, N);
    gemm_kernel<<<Npad / 256, 512, 0, stream>>>(Hb, Agg, wpack + 2 * 32768, bias + 2 * DIM,
                                                Hd, (float*)d_out, stats, 0, N);
}